// Round 2
// 262.697 us; speedup vs baseline: 1.1693x; 1.1693x over previous
//
#include <hip/hip_runtime.h>
#include <math.h>
#include <stdint.h>

// Problem constants (B,N,D,H,HD) = (2, 2048, 1024, 16, 64)
namespace {
constexpr int kB  = 2;
constexpr int kN  = 2048;
constexpr int kD  = 1024;
constexpr int kH  = 16;
constexpr int kM  = kB * kN;   // 4096 rows
}

typedef __attribute__((ext_vector_type(8))) _Float16 f16x8;
typedef __attribute__((ext_vector_type(2))) __fp16   fp16x2;
typedef __attribute__((ext_vector_type(4))) float    f32x4;

__device__ __forceinline__ void split16(float v, _Float16& h, _Float16& l) {
    h = (_Float16)v;
    l = (_Float16)(v - (float)h);
}

// async global->LDS, 16B per lane.  LDS dest = wave-uniform base + lane*16.
__device__ __forceinline__ void gl2lds16(const _Float16* g, _Float16* l) {
    __builtin_amdgcn_global_load_lds(
        (const __attribute__((address_space(1))) void*)g,
        (__attribute__((address_space(3))) void*)l, 16, 0, 0);
}

// ---------------------------------------------------------------------------
// fp32 -> f16 elementwise (x), 8 elems/thread.
// ---------------------------------------------------------------------------
__global__ __launch_bounds__(256)
void cvt16(const float* __restrict__ x, _Float16* __restrict__ o)
{
    const size_t i = ((size_t)blockIdx.x * 256 + threadIdx.x) * 8;
    const float4 a = *(const float4*)(x + i);
    const float4 b = *(const float4*)(x + i + 4);
    _Float16 h[8] = {(_Float16)a.x, (_Float16)a.y, (_Float16)a.z, (_Float16)a.w,
                     (_Float16)b.x, (_Float16)b.y, (_Float16)b.z, (_Float16)b.w};
    *(uint4*)(o + i) = *(uint4*)h;
}

// ---------------------------------------------------------------------------
// Bg prep: pre-arrange (lam/scale)*Bg into the S^T MFMA C-fragment layout so
// attn can load it with 2 x b128 global loads per lane per tile and init the
// QK^T accumulator with it (no LDS staging, no per-element fma with lam).
// Slot t (16 f16): lane=t&63 (q=lane>>4, m=lane&15), i16=(t>>6)&127,
// jt=(t>>13)&31, b=t>>18.  Element js*4+r = (lam/scale)*Bg[b][i16*16+m]
// [jt*64 + js*16 + q*4 + r].
// ---------------------------------------------------------------------------
__global__ __launch_bounds__(256)
void bgprep(const float* __restrict__ Bg, const float* __restrict__ lam_p,
            _Float16* __restrict__ bgC)
{
    const int t    = blockIdx.x * 256 + threadIdx.x;
    const int lane = t & 63;
    const int i16  = (t >> 6) & 127;
    const int jt   = (t >> 13) & 31;
    const int b    = t >> 18;
    const int q    = lane >> 4;
    const int m    = lane & 15;
    const float c  = lam_p[0] * 8.0f;          // lam / scale, scale = 0.125
    const float* src = Bg + ((size_t)b * kN + i16 * 16 + m) * kN + jt * 64 + q * 4;
    _Float16 h[16];
#pragma unroll
    for (int js = 0; js < 4; ++js) {
        const float4 v = *(const float4*)(src + js * 16);
        h[js * 4 + 0] = (_Float16)(c * v.x);
        h[js * 4 + 1] = (_Float16)(c * v.y);
        h[js * 4 + 2] = (_Float16)(c * v.z);
        h[js * 4 + 3] = (_Float16)(c * v.w);
    }
    _Float16* dst = bgC + (size_t)t * 16;
    *(uint4*)(dst)     = *(uint4*)(h);
    *(uint4*)(dst + 8) = *(uint4*)(h + 8);
}

// ---------------------------------------------------------------------------
// One-shot weight prep: W[k][n] fp32 -> Wt[n][k] f16 single plane.
// ---------------------------------------------------------------------------
__global__ __launch_bounds__(256)
void wcvt_t(const float* __restrict__ W, _Float16* __restrict__ Ot)
{
    __shared__ float sT[64][69];
    const int tid = threadIdx.x;
    const int k0 = blockIdx.x << 6;
    const int n0 = blockIdx.y << 6;
#pragma unroll
    for (int rep = 0; rep < 4; ++rep) {
        const int idx = tid + (rep << 8);
        const int kr  = idx >> 4;
        const int c4  = (idx & 15) << 2;
        const float4 v = *(const float4*)(W + (size_t)(k0 + kr) * kD + n0 + c4);
        sT[kr][c4 + 0] = v.x; sT[kr][c4 + 1] = v.y;
        sT[kr][c4 + 2] = v.z; sT[kr][c4 + 3] = v.w;
    }
    __syncthreads();
#pragma unroll
    for (int rep = 0; rep < 2; ++rep) {
        const int slot = tid + (rep << 8);
        const int n  = slot >> 3;
        const int k8 = (slot & 7) << 3;
        _Float16 h8[8];
#pragma unroll
        for (int j = 0; j < 8; ++j) h8[j] = (_Float16)sT[k8 + j][n];
        *(uint4*)(Ot + (size_t)(n0 + n) * kD + k0 + k8) = *(uint4*)h8;
    }
}

// ---------------------------------------------------------------------------
// One-shot weight prep: W[k][n] fp32 -> Wt[n][k] split f16 (h,l) — Wo only.
// ---------------------------------------------------------------------------
__global__ __launch_bounds__(256)
void wsplit_t(const float* __restrict__ W, _Float16* __restrict__ Oh,
              _Float16* __restrict__ Ol)
{
    __shared__ float sT[64][69];
    const int tid = threadIdx.x;
    const int k0 = blockIdx.x << 6;
    const int n0 = blockIdx.y << 6;
#pragma unroll
    for (int rep = 0; rep < 4; ++rep) {
        const int idx = tid + (rep << 8);
        const int kr  = idx >> 4;
        const int c4  = (idx & 15) << 2;
        const float4 v = *(const float4*)(W + (size_t)(k0 + kr) * kD + n0 + c4);
        sT[kr][c4 + 0] = v.x; sT[kr][c4 + 1] = v.y;
        sT[kr][c4 + 2] = v.z; sT[kr][c4 + 3] = v.w;
    }
    __syncthreads();
#pragma unroll
    for (int rep = 0; rep < 2; ++rep) {
        const int slot = tid + (rep << 8);
        const int n  = slot >> 3;
        const int k8 = (slot & 7) << 3;
        _Float16 h8[8], l8[8];
#pragma unroll
        for (int j = 0; j < 8; ++j) split16(sT[k8 + j][n], h8[j], l8[j]);
        *(uint4*)(Oh + (size_t)(n0 + n) * kD + k0 + k8) = *(uint4*)h8;
        *(uint4*)(Ol + (size_t)(n0 + n) * kD + k0 + k8) = *(uint4*)l8;
    }
}

// ---------------------------------------------------------------------------
// m97-style MFMA GEMM.  Tile 128x128, BK=64, 4 waves (2x2 of 64x64).
// Staging: global_load_lds width=16 into XOR-swizzled LDS:
//   sX[row][g] (g = 16B granule 0..7) holds global granule g ^ (row&7)
//   -> frag ds_read_b128 at granule (ks*4+quad)^(m16&7): conflict-free.
// mode 0 (QKV fused): A = x16, B = Wt3 [3072][1024] f16 single, 1-term MFMA.
//   col0<1024 -> Qf ; <2048 -> Kf ; else Vt (transposed).  f16 outputs via
//   LDS-transposed uint4 stores.
// mode 1 (final): A = AO f16, B = Wo h/l 2-term, fp32+bias direct stores
//   (each quad's 16 dwords = one full 64B line).
// Dynamic LDS: mode0 = 34816 B (stage 32K / T 34816 overlay), mode1 = 49152 B.
// ---------------------------------------------------------------------------
__global__ __launch_bounds__(256)
void gemm16(const _Float16* __restrict__ A, const _Float16* __restrict__ Bt,
            const _Float16* __restrict__ Btl,
            const float* __restrict__ b0, const float* __restrict__ b1,
            const float* __restrict__ b2,
            _Float16* __restrict__ Qf, _Float16* __restrict__ Kf,
            _Float16* __restrict__ Vt, float* __restrict__ outF, int mode)
{
    extern __shared__ _Float16 dyn[];
    _Float16* sA  = dyn;                 // [128][64]
    _Float16* sB  = dyn + 128 * 64;      // [128][64]
    _Float16* sBl = dyn + 2 * 128 * 64;  // [128][64] (mode 1 only)

    const int tid  = threadIdx.x;
    const int lane = tid & 63;
    const int w    = tid >> 6;
    const int quad = lane >> 4;
    const int m16  = lane & 15;
    const int wrow = (w >> 1) << 6;
    const int wcol = (w & 1) << 6;

    const int row0 = blockIdx.y << 7;
    const int col0 = blockIdx.x << 7;

    f32x4 acc[4][4];
#pragma unroll
    for (int mr = 0; mr < 4; ++mr)
#pragma unroll
        for (int nr = 0; nr < 4; ++nr) acc[mr][nr] = (f32x4){0.f, 0.f, 0.f, 0.f};

    const int srl = lane >> 3;           // staging row within 8-row chunk
    const int sg  = lane & 7;            // staging granule slot

    // stage a [128][64]-f16 tile; wave w covers rows [w*32, w*32+32)
    auto stage = [&](const _Float16* gsrc, _Float16* ldst) {
#pragma unroll
        for (int t = 0; t < 4; ++t) {
            const int rr = (w << 5) + (t << 3);          // uniform chunk base
            const int r  = rr + srl;
            const int gg = (sg ^ (r & 7)) << 3;          // swizzled k-granule
            gl2lds16(gsrc + (size_t)r * kD + gg, ldst + rr * 64);
        }
    };

    for (int kt = 0; kt < 16; ++kt) {
        const int k0 = kt << 6;
        stage(A  + (size_t)row0 * kD + k0, sA);
        stage(Bt + (size_t)col0 * kD + k0, sB);
        if (mode == 1) stage(Btl + (size_t)col0 * kD + k0, sBl);
        __syncthreads();                 // drains vmcnt -> tile visible

#pragma unroll
        for (int ks = 0; ks < 2; ++ks) {
            const int sw = (((ks << 2) | quad) ^ (m16 & 7)) << 3;
            f16x8 af[4], bf[4], blf[4];
#pragma unroll
            for (int mr = 0; mr < 4; ++mr)
                af[mr] = *(const f16x8*)(sA + (wrow + mr * 16 + m16) * 64 + sw);
#pragma unroll
            for (int nr = 0; nr < 4; ++nr) {
                const int off = (wcol + nr * 16 + m16) * 64 + sw;
                bf[nr] = *(const f16x8*)(sB + off);
                if (mode == 1) blf[nr] = *(const f16x8*)(sBl + off);
            }
#pragma unroll
            for (int mr = 0; mr < 4; ++mr)
#pragma unroll
                for (int nr = 0; nr < 4; ++nr) {
                    acc[mr][nr] = __builtin_amdgcn_mfma_f32_16x16x32_f16(af[mr], bf[nr], acc[mr][nr], 0, 0, 0);
                    if (mode == 1)
                        acc[mr][nr] = __builtin_amdgcn_mfma_f32_16x16x32_f16(af[mr], blf[nr], acc[mr][nr], 0, 0, 0);
                }
        }
        __syncthreads();                 // reads done before next stage
    }

    // ---- epilogue ----
    if (mode == 1) {                     // fp32 + bias, direct stores
#pragma unroll
        for (int mr = 0; mr < 4; ++mr)
#pragma unroll
            for (int nr = 0; nr < 4; ++nr)
#pragma unroll
                for (int r = 0; r < 4; ++r) {
                    const int row = row0 + wrow + mr * 16 + quad * 4 + r;
                    const int col = col0 + wcol + nr * 16 + m16;
                    outF[(size_t)row * kD + col] = acc[mr][nr][r] + b0[col];
                }
        return;
    }

    const float* bias; int cb; _Float16* dst = nullptr; bool vmode = false;
    if (col0 < 1024)      { bias = b0; cb = col0;        dst = Qf; }
    else if (col0 < 2048) { bias = b1; cb = col0 - 1024; dst = Kf; }
    else                  { bias = b2; cb = col0 - 2048; vmode = true; }

    _Float16* T = dyn;                   // [128][136] overlay

    if (!vmode) {                        // Q / K: [row][col] f16
#pragma unroll
        for (int mr = 0; mr < 4; ++mr)
#pragma unroll
            for (int nr = 0; nr < 4; ++nr)
#pragma unroll
                for (int r = 0; r < 4; ++r) {
                    const int row = wrow + mr * 16 + quad * 4 + r;
                    const int cl  = wcol + nr * 16 + m16;
                    T[row * 136 + cl] = (_Float16)(acc[mr][nr][r] + bias[cb + cl]);
                }
        __syncthreads();
#pragma unroll
        for (int rep = 0; rep < 8; ++rep) {
            const int slot = tid + (rep << 8);
            const int row = slot >> 4;
            const int c8  = (slot & 15) << 3;
            *(uint4*)(dst + (size_t)(row0 + row) * kD + cb + c8) =
                *(const uint4*)(T + row * 136 + c8);
        }
    } else {                             // V: transposed [d][tok] f16
#pragma unroll
        for (int mr = 0; mr < 4; ++mr)
#pragma unroll
            for (int nr = 0; nr < 4; ++nr)
#pragma unroll
                for (int r = 0; r < 4; ++r) {
                    const int tok = wrow + mr * 16 + quad * 4 + r;
                    const int cl  = wcol + nr * 16 + m16;
                    T[cl * 136 + tok] = (_Float16)(acc[mr][nr][r] + bias[cb + cl]);
                }
        __syncthreads();
        const int b  = row0 >> 11;
        const int n0 = row0 & (kN - 1);
#pragma unroll
        for (int rep = 0; rep < 8; ++rep) {
            const int slot = tid + (rep << 8);
            const int cl = slot >> 4;
            const int t8 = (slot & 15) << 3;
            *(uint4*)(Vt + ((size_t)(b * kD + cb + cl)) * kN + n0 + t8) =
                *(const uint4*)(T + cl * 136 + t8);
        }
    }
}

// ---------------------------------------------------------------------------
// MFMA flash attention, v2: swapped-operand QK^T (S^T = K Q^T) so each lane's
// P-row is lane-local (i = m16), bias folded into the MFMA C-operand from a
// pre-arranged global buffer (no sB LDS staging), P packed via v_cvt_pkrtz
// into 4 x b64 LDS writes.  LDS ops/thread/jt: 20 b128 + 4 b64 (was 22 b128 +
// 32 sub-dword) -- the kernel was measured LDS-issue-bound (~282K LDS
// cyc/CU ~= 118us).  Flat softmax p = exp(val-4) unchanged.
// LDS 36,864 B.  sP row stride 72 f16: b64 writes 4/bank, b128 reads 8/bank.
// ---------------------------------------------------------------------------
__global__ __launch_bounds__(512)
void attn_f16(const _Float16* __restrict__ Qf, const _Float16* __restrict__ Kf,
              const _Float16* __restrict__ Vt, const _Float16* __restrict__ BgC,
              _Float16* __restrict__ AOh)
{
    __shared__ _Float16 sK[64][72];
    __shared__ _Float16 sV[64][72];
    __shared__ _Float16 sP[8][16][72];

    const int tid  = threadIdx.x;
    const int lane = tid & 63;
    const int w    = tid >> 6;       // 0..7
    const int quad = lane >> 4;
    const int m16  = lane & 15;

    const int qt = blockIdx.x;       // 0..15
    const int bh = blockIdx.y;       // 0..31
    const int b  = bh >> 4;
    const int h  = bh & 15;
    const int i0 = qt << 7;

    // ---- Q B-frags (B-row = i = m16), held all kernel ----
    f16x8 qf[2];
    {
        const size_t qoff = (size_t)(b * kN + i0 + w * 16 + m16) * kD + h * 64 + quad * 8;
        qf[0] = *(const f16x8*)(Qf + qoff);
        qf[1] = *(const f16x8*)(Qf + qoff + 32);
    }

    f32x4 O[4];
#pragma unroll
    for (int ds = 0; ds < 4; ++ds) O[ds] = (f32x4){0.f, 0.f, 0.f, 0.f};
    float lsum = 0.f;                // lane-local: row i = m16 partial sum

    const int krow = tid >> 3;       // 0..63
    const int kc8  = (tid & 7) << 3;

    // per-lane BgC slot base: (((b*32 + jt)*128 + qt*8 + w)*64 + lane)*16
    const _Float16* bgbase =
        BgC + (((size_t)b * 32 * 128 + (qt * 8 + w)) * 64 + lane) * 16;
    constexpr size_t kBgJt = (size_t)128 * 64 * 16;   // per-jt stride (f16)

    uint4 kp, vp;
    f16x8 bg0, bg1;
    auto loadTile = [&](int jt) {
        const int j0 = jt << 6;
        kp = *(const uint4*)(Kf + (size_t)(b * kN + j0 + krow) * kD + h * 64 + kc8);
        vp = *(const uint4*)(Vt + (size_t)(b * kD + h * 64 + krow) * kN + j0 + kc8);
        const _Float16* bp = bgbase + (size_t)jt * kBgJt;
        bg0 = *(const f16x8*)(bp);
        bg1 = *(const f16x8*)(bp + 8);
    };

    loadTile(0);

    for (int jt = 0; jt < kN / 64; ++jt) {
        __syncthreads();
        *(uint4*)&sK[krow][kc8] = kp;
        *(uint4*)&sV[krow][kc8] = vp;
        __syncthreads();

        // ---- acc init from BgC: sacc = (lam/scale)*Bg at S^T positions ----
        f32x4 sacc[4];
#pragma unroll
        for (int r = 0; r < 4; ++r) {
            sacc[0][r] = (float)bg0[r];
            sacc[1][r] = (float)bg0[4 + r];
            sacc[2][r] = (float)bg1[r];
            sacc[3][r] = (float)bg1[4 + r];
        }

        if (jt < kN / 64 - 1) loadTile(jt + 1);   // overlaps compute phase

        // ---- S^T = K Q^T + C (8 MFMA); lane holds i=m16, j=js*16+quad*4+r
#pragma unroll
        for (int ks = 0; ks < 2; ++ks)
#pragma unroll
            for (int js = 0; js < 4; ++js) {
                const f16x8 kf = *(const f16x8*)&sK[js * 16 + m16][ks * 32 + quad * 8];
                sacc[js] = __builtin_amdgcn_mfma_f32_16x16x32_f16(kf, qf[ks], sacc[js], 0, 0, 0);
            }

        // ---- flat softmax numerator: p = exp(val*scale - 4), packed store
#pragma unroll
        for (int js = 0; js < 4; ++js) {
            float p[4];
#pragma unroll
            for (int r = 0; r < 4; ++r)
                p[r] = __expf(fmaf(sacc[js][r], 0.125f, -4.0f));
            lsum += (p[0] + p[1]) + (p[2] + p[3]);
            union { fp16x2 h[2]; uint2 u; } pk;
            pk.h[0] = __builtin_amdgcn_cvt_pkrtz(p[0], p[1]);
            pk.h[1] = __builtin_amdgcn_cvt_pkrtz(p[2], p[3]);
            *(uint2*)&sP[w][m16][js * 16 + quad * 4] = pk.u;
        }
        __asm__ volatile("s_waitcnt lgkmcnt(0)" ::: "memory");

        // ---- O += P V (8 MFMA); pf is lane-local row m16 ----
#pragma unroll
        for (int ks = 0; ks < 2; ++ks) {
            const f16x8 pf = *(const f16x8*)&sP[w][m16][ks * 32 + quad * 8];
#pragma unroll
            for (int ds = 0; ds < 4; ++ds) {
                const f16x8 vf = *(const f16x8*)&sV[ds * 16 + m16][ks * 32 + quad * 8];
                O[ds] = __builtin_amdgcn_mfma_f32_16x16x32_f16(pf, vf, O[ds], 0, 0, 0);
            }
        }
    }

    // ---- l: sum quad partials (rows i=m16), redistribute to O-row layout --
    float l = lsum;
    l += __shfl_xor(l, 16, 64);
    l += __shfl_xor(l, 32, 64);      // every lane: full row-sum for i = m16

    const int orow = b * kN + i0 + w * 16 + quad * 4;
#pragma unroll
    for (int r = 0; r < 4; ++r) {
        const float inv = 1.0f / __shfl(l, quad * 4 + r, 64);
#pragma unroll
        for (int ds = 0; ds < 4; ++ds)
            AOh[(size_t)(orow + r) * kD + h * 64 + ds * 16 + m16] =
                (_Float16)(O[ds][r] * inv);
    }
}

// ---------------------------------------------------------------------------
extern "C" void kernel_launch(void* const* d_in, const int* in_sizes, int n_in,
                              void* d_out, int out_size, void* d_ws, size_t ws_size,
                              hipStream_t stream)
{
    (void)in_sizes; (void)n_in; (void)out_size; (void)ws_size;

    const float* x   = (const float*)d_in[0];
    const float* Bg  = (const float*)d_in[1];
    const float* Wq  = (const float*)d_in[2];
    const float* bq  = (const float*)d_in[3];
    const float* Wk  = (const float*)d_in[4];
    const float* bk  = (const float*)d_in[5];
    const float* Wv  = (const float*)d_in[6];
    const float* bv  = (const float*)d_in[7];
    const float* Wo  = (const float*)d_in[8];
    const float* bo  = (const float*)d_in[9];
    const float* lam = (const float*)d_in[10];
    float* out = (float*)d_out;
    _Float16* ws16 = (_Float16*)d_ws;

    // Workspace (f16 elems): 4*4M + 5*1M + 8M = 29M elems = 58 MiB
    constexpr size_t kQKV = (size_t)kM * kD;        // 4,194,304
    constexpr size_t kW   = (size_t)kD * kD;        // 1,048,576
    _Float16* Qf   = ws16;
    _Float16* Kf   = ws16 + 1 * kQKV;
    _Float16* Vt   = ws16 + 2 * kQKV;
    _Float16* x16  = ws16 + 3 * kQKV;
    _Float16* AOh  = x16;               // x16 dead after QKV GEMM (stream order)
    _Float16* Wt3  = ws16 + 4 * kQKV;   // [3072][1024] single-plane QKV weights
    _Float16* Woth = Wt3 + 3 * kW;
    _Float16* Wotl = Woth + kW;
    _Float16* BgC  = Wotl + kW;         // 8M f16: C-fragment-layout (lam/scale)*Bg

    dim3 blk(256);

    // 1) one-shot prep
    cvt16<<<dim3(2048), blk, 0, stream>>>(x, x16);
    bgprep<<<dim3(2048), blk, 0, stream>>>(Bg, lam, BgC);
    dim3 wg(kD / 64, kD / 64);          // (16,16)
    wcvt_t  <<<wg, blk, 0, stream>>>(Wq, Wt3);
    wcvt_t  <<<wg, blk, 0, stream>>>(Wk, Wt3 + kW);
    wcvt_t  <<<wg, blk, 0, stream>>>(Wv, Wt3 + 2 * kW);
    wsplit_t<<<wg, blk, 0, stream>>>(Wo, Woth, Wotl);

    // 2) fused QKV projection: (24, 32) = 768 blocks, 1-term
    gemm16<<<dim3(3 * kD / 128, kM / 128), blk, 34816, stream>>>(
        x16, Wt3, nullptr, bq, bk, bv, Qf, Kf, Vt, nullptr, 0);

    // 3) attention: (16, 32) = 512 blocks x 512 threads
    attn_f16<<<dim3(kN / 128, kB * kH), dim3(512), 0, stream>>>(
        Qf, Kf, Vt, BgC, AOh);

    // 4) output projection: (8, 32) = 256 blocks, 2-term
    gemm16<<<dim3(kD / 128, kM / 128), blk, 49152, stream>>>(
        AOh, Woth, Wotl, bo, nullptr, nullptr,
        nullptr, nullptr, nullptr, out, 1);
}

// Round 3
// 260.280 us; speedup vs baseline: 1.1802x; 1.0093x over previous
//
#include <hip/hip_runtime.h>
#include <math.h>
#include <stdint.h>

// Problem constants (B,N,D,H,HD) = (2, 2048, 1024, 16, 64)
namespace {
constexpr int kB  = 2;
constexpr int kN  = 2048;
constexpr int kD  = 1024;
constexpr int kH  = 16;
constexpr int kM  = kB * kN;   // 4096 rows
}

typedef __attribute__((ext_vector_type(8))) _Float16 f16x8;
typedef __attribute__((ext_vector_type(2))) __fp16   fp16x2;
typedef __attribute__((ext_vector_type(4))) float    f32x4;

__device__ __forceinline__ void split16(float v, _Float16& h, _Float16& l) {
    h = (_Float16)v;
    l = (_Float16)(v - (float)h);
}

// async global->LDS, 16B per lane.  LDS dest = wave-uniform base + lane*16.
__device__ __forceinline__ void gl2lds16(const _Float16* g, _Float16* l) {
    __builtin_amdgcn_global_load_lds(
        (const __attribute__((address_space(1))) void*)g,
        (__attribute__((address_space(3))) void*)l, 16, 0, 0);
}

// ---------------------------------------------------------------------------
// fp32 -> f16 elementwise (x), 8 elems/thread.
// ---------------------------------------------------------------------------
__global__ __launch_bounds__(256)
void cvt16(const float* __restrict__ x, _Float16* __restrict__ o)
{
    const size_t i = ((size_t)blockIdx.x * 256 + threadIdx.x) * 8;
    const float4 a = *(const float4*)(x + i);
    const float4 b = *(const float4*)(x + i + 4);
    _Float16 h[8] = {(_Float16)a.x, (_Float16)a.y, (_Float16)a.z, (_Float16)a.w,
                     (_Float16)b.x, (_Float16)b.y, (_Float16)b.z, (_Float16)b.w};
    *(uint4*)(o + i) = *(uint4*)h;
}

// ---------------------------------------------------------------------------
// Bg prep: pre-arrange (lam/scale)*Bg into the S^T MFMA C-fragment layout so
// attn can load it with 2 x b128 global loads per lane per tile and init the
// QK^T accumulator with it (no LDS staging, no per-element fma with lam).
// Slot t (16 f16): lane=t&63 (q=lane>>4, m=lane&15), i16=(t>>6)&127,
// jt=(t>>13)&31, b=t>>18.  Element js*4+r = (lam/scale)*Bg[b][i16*16+m]
// [jt*64 + js*16 + q*4 + r].  (Token order of sK is NATURAL, so no perm here.)
// ---------------------------------------------------------------------------
__global__ __launch_bounds__(256)
void bgprep(const float* __restrict__ Bg, const float* __restrict__ lam_p,
            _Float16* __restrict__ bgC)
{
    const int t    = blockIdx.x * 256 + threadIdx.x;
    const int lane = t & 63;
    const int i16  = (t >> 6) & 127;
    const int jt   = (t >> 13) & 31;
    const int b    = t >> 18;
    const int q    = lane >> 4;
    const int m    = lane & 15;
    const float c  = lam_p[0] * 8.0f;          // lam / scale, scale = 0.125
    const float* src = Bg + ((size_t)b * kN + i16 * 16 + m) * kN + jt * 64 + q * 4;
    _Float16 h[16];
#pragma unroll
    for (int js = 0; js < 4; ++js) {
        const float4 v = *(const float4*)(src + js * 16);
        h[js * 4 + 0] = (_Float16)(c * v.x);
        h[js * 4 + 1] = (_Float16)(c * v.y);
        h[js * 4 + 2] = (_Float16)(c * v.z);
        h[js * 4 + 3] = (_Float16)(c * v.w);
    }
    _Float16* dst = bgC + (size_t)t * 16;
    *(uint4*)(dst)     = *(uint4*)(h);
    *(uint4*)(dst + 8) = *(uint4*)(h + 8);
}

// ---------------------------------------------------------------------------
// One-shot weight prep: W[k][n] fp32 -> Wt[n][k] f16 single plane.
// ---------------------------------------------------------------------------
__global__ __launch_bounds__(256)
void wcvt_t(const float* __restrict__ W, _Float16* __restrict__ Ot)
{
    __shared__ float sT[64][69];
    const int tid = threadIdx.x;
    const int k0 = blockIdx.x << 6;
    const int n0 = blockIdx.y << 6;
#pragma unroll
    for (int rep = 0; rep < 4; ++rep) {
        const int idx = tid + (rep << 8);
        const int kr  = idx >> 4;
        const int c4  = (idx & 15) << 2;
        const float4 v = *(const float4*)(W + (size_t)(k0 + kr) * kD + n0 + c4);
        sT[kr][c4 + 0] = v.x; sT[kr][c4 + 1] = v.y;
        sT[kr][c4 + 2] = v.z; sT[kr][c4 + 3] = v.w;
    }
    __syncthreads();
#pragma unroll
    for (int rep = 0; rep < 2; ++rep) {
        const int slot = tid + (rep << 8);
        const int n  = slot >> 3;
        const int k8 = (slot & 7) << 3;
        _Float16 h8[8];
#pragma unroll
        for (int j = 0; j < 8; ++j) h8[j] = (_Float16)sT[k8 + j][n];
        *(uint4*)(Ot + (size_t)(n0 + n) * kD + k0 + k8) = *(uint4*)h8;
    }
}

// ---------------------------------------------------------------------------
// One-shot weight prep: W[k][n] fp32 -> Wt[n][k] split f16 (h,l) — Wo only.
// ---------------------------------------------------------------------------
__global__ __launch_bounds__(256)
void wsplit_t(const float* __restrict__ W, _Float16* __restrict__ Oh,
              _Float16* __restrict__ Ol)
{
    __shared__ float sT[64][69];
    const int tid = threadIdx.x;
    const int k0 = blockIdx.x << 6;
    const int n0 = blockIdx.y << 6;
#pragma unroll
    for (int rep = 0; rep < 4; ++rep) {
        const int idx = tid + (rep << 8);
        const int kr  = idx >> 4;
        const int c4  = (idx & 15) << 2;
        const float4 v = *(const float4*)(W + (size_t)(k0 + kr) * kD + n0 + c4);
        sT[kr][c4 + 0] = v.x; sT[kr][c4 + 1] = v.y;
        sT[kr][c4 + 2] = v.z; sT[kr][c4 + 3] = v.w;
    }
    __syncthreads();
#pragma unroll
    for (int rep = 0; rep < 2; ++rep) {
        const int slot = tid + (rep << 8);
        const int n  = slot >> 3;
        const int k8 = (slot & 7) << 3;
        _Float16 h8[8], l8[8];
#pragma unroll
        for (int j = 0; j < 8; ++j) split16(sT[k8 + j][n], h8[j], l8[j]);
        *(uint4*)(Oh + (size_t)(n0 + n) * kD + k0 + k8) = *(uint4*)h8;
        *(uint4*)(Ol + (size_t)(n0 + n) * kD + k0 + k8) = *(uint4*)l8;
    }
}

// ---------------------------------------------------------------------------
// m97-style MFMA GEMM.  Tile 128x128, BK=64, 4 waves (2x2 of 64x64).
// Staging: global_load_lds width=16 into XOR-swizzled LDS:
//   sX[row][g] (g = 16B granule 0..7) holds global granule g ^ (row&7)
//   -> frag ds_read_b128 at granule (ks*4+quad)^(m16&7): conflict-free.
// mode 0 (QKV fused): A = x16, B = Wt3 [3072][1024] f16 single, 1-term MFMA.
//   col0<1024 -> Qf ; <2048 -> Kf ; else Vt (transposed, TOKEN-PERMUTED:
//   within each 64-token group, token rho is stored at column
//   sigma = bits{rho5, rho3, rho2, rho4, rho1, rho0} — so the attention
//   kernel's packed-P registers feed PV MFMAs directly, no P staging).
// mode 1 (final): A = AO f16, B = Wo h/l 2-term, fp32+bias direct stores.
// Dynamic LDS: mode0 = 34816 B (stage 32K / T 34816 overlay), mode1 = 49152 B.
// ---------------------------------------------------------------------------
__global__ __launch_bounds__(256)
void gemm16(const _Float16* __restrict__ A, const _Float16* __restrict__ Bt,
            const _Float16* __restrict__ Btl,
            const float* __restrict__ b0, const float* __restrict__ b1,
            const float* __restrict__ b2,
            _Float16* __restrict__ Qf, _Float16* __restrict__ Kf,
            _Float16* __restrict__ Vt, float* __restrict__ outF, int mode)
{
    extern __shared__ _Float16 dyn[];
    _Float16* sA  = dyn;                 // [128][64]
    _Float16* sB  = dyn + 128 * 64;      // [128][64]
    _Float16* sBl = dyn + 2 * 128 * 64;  // [128][64] (mode 1 only)

    const int tid  = threadIdx.x;
    const int lane = tid & 63;
    const int w    = tid >> 6;
    const int quad = lane >> 4;
    const int m16  = lane & 15;
    const int wrow = (w >> 1) << 6;
    const int wcol = (w & 1) << 6;

    const int row0 = blockIdx.y << 7;
    const int col0 = blockIdx.x << 7;

    f32x4 acc[4][4];
#pragma unroll
    for (int mr = 0; mr < 4; ++mr)
#pragma unroll
        for (int nr = 0; nr < 4; ++nr) acc[mr][nr] = (f32x4){0.f, 0.f, 0.f, 0.f};

    const int srl = lane >> 3;           // staging row within 8-row chunk
    const int sg  = lane & 7;            // staging granule slot

    // stage a [128][64]-f16 tile; wave w covers rows [w*32, w*32+32)
    auto stage = [&](const _Float16* gsrc, _Float16* ldst) {
#pragma unroll
        for (int t = 0; t < 4; ++t) {
            const int rr = (w << 5) + (t << 3);          // uniform chunk base
            const int r  = rr + srl;
            const int gg = (sg ^ (r & 7)) << 3;          // swizzled k-granule
            gl2lds16(gsrc + (size_t)r * kD + gg, ldst + rr * 64);
        }
    };

    for (int kt = 0; kt < 16; ++kt) {
        const int k0 = kt << 6;
        stage(A  + (size_t)row0 * kD + k0, sA);
        stage(Bt + (size_t)col0 * kD + k0, sB);
        if (mode == 1) stage(Btl + (size_t)col0 * kD + k0, sBl);
        __syncthreads();                 // drains vmcnt -> tile visible

#pragma unroll
        for (int ks = 0; ks < 2; ++ks) {
            const int sw = (((ks << 2) | quad) ^ (m16 & 7)) << 3;
            f16x8 af[4], bf[4], blf[4];
#pragma unroll
            for (int mr = 0; mr < 4; ++mr)
                af[mr] = *(const f16x8*)(sA + (wrow + mr * 16 + m16) * 64 + sw);
#pragma unroll
            for (int nr = 0; nr < 4; ++nr) {
                const int off = (wcol + nr * 16 + m16) * 64 + sw;
                bf[nr] = *(const f16x8*)(sB + off);
                if (mode == 1) blf[nr] = *(const f16x8*)(sBl + off);
            }
#pragma unroll
            for (int mr = 0; mr < 4; ++mr)
#pragma unroll
                for (int nr = 0; nr < 4; ++nr) {
                    acc[mr][nr] = __builtin_amdgcn_mfma_f32_16x16x32_f16(af[mr], bf[nr], acc[mr][nr], 0, 0, 0);
                    if (mode == 1)
                        acc[mr][nr] = __builtin_amdgcn_mfma_f32_16x16x32_f16(af[mr], blf[nr], acc[mr][nr], 0, 0, 0);
                }
        }
        __syncthreads();                 // reads done before next stage
    }

    // ---- epilogue ----
    if (mode == 1) {                     // fp32 + bias, direct stores
#pragma unroll
        for (int mr = 0; mr < 4; ++mr)
#pragma unroll
            for (int nr = 0; nr < 4; ++nr)
#pragma unroll
                for (int r = 0; r < 4; ++r) {
                    const int row = row0 + wrow + mr * 16 + quad * 4 + r;
                    const int col = col0 + wcol + nr * 16 + m16;
                    outF[(size_t)row * kD + col] = acc[mr][nr][r] + b0[col];
                }
        return;
    }

    const float* bias; int cb; _Float16* dst = nullptr; bool vmode = false;
    if (col0 < 1024)      { bias = b0; cb = col0;        dst = Qf; }
    else if (col0 < 2048) { bias = b1; cb = col0 - 1024; dst = Kf; }
    else                  { bias = b2; cb = col0 - 2048; vmode = true; }

    _Float16* T = dyn;                   // [128][136] overlay

    if (!vmode) {                        // Q / K: [row][col] f16
#pragma unroll
        for (int mr = 0; mr < 4; ++mr)
#pragma unroll
            for (int nr = 0; nr < 4; ++nr)
#pragma unroll
                for (int r = 0; r < 4; ++r) {
                    const int row = wrow + mr * 16 + quad * 4 + r;
                    const int cl  = wcol + nr * 16 + m16;
                    T[row * 136 + cl] = (_Float16)(acc[mr][nr][r] + bias[cb + cl]);
                }
        __syncthreads();
#pragma unroll
        for (int rep = 0; rep < 8; ++rep) {
            const int slot = tid + (rep << 8);
            const int row = slot >> 4;
            const int c8  = (slot & 15) << 3;
            *(uint4*)(dst + (size_t)(row0 + row) * kD + cb + c8) =
                *(const uint4*)(T + row * 136 + c8);
        }
    } else {                             // V: transposed [d][tokP] f16, permuted
#pragma unroll
        for (int mr = 0; mr < 4; ++mr)
#pragma unroll
            for (int nr = 0; nr < 4; ++nr)
#pragma unroll
                for (int r = 0; r < 4; ++r) {
                    const int tok  = wrow + mr * 16 + quad * 4 + r;
                    // sigma bits <- tok bits {5,3,2,4,1,0}; bit 6 kept
                    const int tokP = (tok & 64) | (tok & 32) |
                                     (((tok >> 2) & 3) << 3) |
                                     (((tok >> 4) & 1) << 2) | (tok & 3);
                    const int cl   = wcol + nr * 16 + m16;
                    T[cl * 136 + tokP] = (_Float16)(acc[mr][nr][r] + bias[cb + cl]);
                }
        __syncthreads();
        const int b  = row0 >> 11;
        const int n0 = row0 & (kN - 1);
#pragma unroll
        for (int rep = 0; rep < 8; ++rep) {
            const int slot = tid + (rep << 8);
            const int cl = slot >> 4;
            const int t8 = (slot & 15) << 3;
            *(uint4*)(Vt + ((size_t)(b * kD + cb + cl)) * kN + n0 + t8) =
                *(const uint4*)(T + cl * 136 + t8);
        }
    }
}

// ---------------------------------------------------------------------------
// MFMA flash attention, v3: P never leaves registers.  Swapped-operand QK^T
// (S^T = K Q^T + BgC) gives each lane p at token slots js*16+quad*4+r; the
// PV A-operand needs slots ks*32+quad*8+e.  Vt's token order is pre-permuted
// (in the QKV GEMM epilogue) by exactly this bit shuffle, so the packed
// cvt_pkrtz dwords ARE the PV A-frags.  sP, its LDS ops, and the lgkmcnt(0)
// drain are gone.  Freed LDS funds double-buffered sK/sV -> 1 barrier/jt,
// ~2-tile global prefetch distance.  LDS/thread/jt: 18 b128 (was 20 b128 +
// 4 b64 + conflicts).  LDS total 36,864 B (2x2x64x72 f16).
// ---------------------------------------------------------------------------
__global__ __launch_bounds__(512, 4)
void attn_f16(const _Float16* __restrict__ Qf, const _Float16* __restrict__ Kf,
              const _Float16* __restrict__ Vt, const _Float16* __restrict__ BgC,
              _Float16* __restrict__ AOh)
{
    __shared__ _Float16 sK[2][64][72];
    __shared__ _Float16 sV[2][64][72];

    const int tid  = threadIdx.x;
    const int lane = tid & 63;
    const int w    = tid >> 6;       // 0..7
    const int quad = lane >> 4;
    const int m16  = lane & 15;

    const int qt = blockIdx.x;       // 0..15
    const int bh = blockIdx.y;       // 0..31
    const int b  = bh >> 4;
    const int h  = bh & 15;
    const int i0 = qt << 7;

    // ---- Q B-frags (B-row = i = m16), held all kernel ----
    f16x8 qf[2];
    {
        const size_t qoff = (size_t)(b * kN + i0 + w * 16 + m16) * kD + h * 64 + quad * 8;
        qf[0] = *(const f16x8*)(Qf + qoff);
        qf[1] = *(const f16x8*)(Qf + qoff + 32);
    }

    f32x4 O[4];
#pragma unroll
    for (int ds = 0; ds < 4; ++ds) O[ds] = (f32x4){0.f, 0.f, 0.f, 0.f};
    float lsum = 0.f;                // lane-local: row i = m16 partial sum

    const int krow = tid >> 3;       // 0..63
    const int kc8  = (tid & 7) << 3;

    // per-lane BgC slot base: (((b*32 + jt)*128 + qt*8 + w)*64 + lane)*16
    const _Float16* bgbase =
        BgC + (((size_t)b * 32 * 128 + (qt * 8 + w)) * 64 + lane) * 16;
    constexpr size_t kBgJt = (size_t)128 * 64 * 16;   // per-jt stride (f16)

    auto loadT = [&](int jt, uint4& kp, uint4& vp, f16x8& g0, f16x8& g1) {
        const int j0 = jt << 6;
        kp = *(const uint4*)(Kf + (size_t)(b * kN + j0 + krow) * kD + h * 64 + kc8);
        vp = *(const uint4*)(Vt + (size_t)(b * kD + h * 64 + krow) * kN + j0 + kc8);
        const _Float16* bp = bgbase + (size_t)jt * kBgJt;
        g0 = *(const f16x8*)(bp);
        g1 = *(const f16x8*)(bp + 8);
    };

    auto phaseCompute = [&](const _Float16 (&Kt)[64][72],
                            const _Float16 (&Vs)[64][72],
                            const f16x8& g0, const f16x8& g1) {
        f32x4 sacc[4];
#pragma unroll
        for (int r = 0; r < 4; ++r) {
            sacc[0][r] = (float)g0[r];
            sacc[1][r] = (float)g0[4 + r];
            sacc[2][r] = (float)g1[r];
            sacc[3][r] = (float)g1[4 + r];
        }
        __builtin_amdgcn_s_setprio(1);
#pragma unroll
        for (int ks = 0; ks < 2; ++ks)
#pragma unroll
            for (int js = 0; js < 4; ++js) {
                const f16x8 kf = *(const f16x8*)&Kt[js * 16 + m16][ks * 32 + quad * 8];
                sacc[js] = __builtin_amdgcn_mfma_f32_16x16x32_f16(kf, qf[ks], sacc[js], 0, 0, 0);
            }
        __builtin_amdgcn_s_setprio(0);

        // flat softmax numerator: p = exp(val*scale - 4); pack to PV A-frags
        union { f16x8 v; unsigned u[4]; } pf[2];
#pragma unroll
        for (int js = 0; js < 4; ++js) {
            float p[4];
#pragma unroll
            for (int r = 0; r < 4; ++r)
                p[r] = __expf(fmaf(sacc[js][r], 0.125f, -4.0f));
            lsum += (p[0] + p[1]) + (p[2] + p[3]);
            const fp16x2 lo = __builtin_amdgcn_cvt_pkrtz(p[0], p[1]);
            const fp16x2 hi = __builtin_amdgcn_cvt_pkrtz(p[2], p[3]);
            union { fp16x2 h; unsigned u; } ua, ub;
            ua.h = lo; ub.h = hi;
            pf[js >> 1].u[(js & 1) * 2 + 0] = ua.u;
            pf[js >> 1].u[(js & 1) * 2 + 1] = ub.u;
        }

        __builtin_amdgcn_s_setprio(1);
#pragma unroll
        for (int ks = 0; ks < 2; ++ks)
#pragma unroll
            for (int ds = 0; ds < 4; ++ds) {
                const f16x8 vf = *(const f16x8*)&Vs[ds * 16 + m16][ks * 32 + quad * 8];
                O[ds] = __builtin_amdgcn_mfma_f32_16x16x32_f16(pf[ks].v, vf, O[ds], 0, 0, 0);
            }
        __builtin_amdgcn_s_setprio(0);
    };

    uint4 kp0, vp0, kp1, vp1;
    f16x8 bgA0, bgA1, bgB0, bgB1;

    // prologue: tile 0 staged to buf0; tile 1 held in regs
    loadT(0, kp0, vp0, bgA0, bgA1);
    *(uint4*)&sK[0][krow][kc8] = kp0;
    *(uint4*)&sV[0][krow][kc8] = vp0;
    loadT(1, kp1, vp1, bgB0, bgB1);
    __syncthreads();

    for (int t = 0; t < kN / 64; t += 2) {
        // ---- phase 0: compute tile t from buf0 ----
        phaseCompute(sK[0], sV[0], bgA0, bgA1);
        if (t + 2 < kN / 64) loadT(t + 2, kp0, vp0, bgA0, bgA1);
        *(uint4*)&sK[1][krow][kc8] = kp1;      // stage tile t+1
        *(uint4*)&sV[1][krow][kc8] = vp1;
        __syncthreads();

        // ---- phase 1: compute tile t+1 from buf1 ----
        phaseCompute(sK[1], sV[1], bgB0, bgB1);
        if (t + 3 < kN / 64) loadT(t + 3, kp1, vp1, bgB0, bgB1);
        if (t + 2 < kN / 64) {
            *(uint4*)&sK[0][krow][kc8] = kp0;  // stage tile t+2
            *(uint4*)&sV[0][krow][kc8] = vp0;
        }
        __syncthreads();
    }

    // ---- l: sum quad partials (rows i=m16), redistribute to O-row layout --
    float l = lsum;
    l += __shfl_xor(l, 16, 64);
    l += __shfl_xor(l, 32, 64);      // every lane: full row-sum for i = m16

    const int orow = b * kN + i0 + w * 16 + quad * 4;
#pragma unroll
    for (int r = 0; r < 4; ++r) {
        const float inv = 1.0f / __shfl(l, quad * 4 + r, 64);
#pragma unroll
        for (int ds = 0; ds < 4; ++ds)
            AOh[(size_t)(orow + r) * kD + h * 64 + ds * 16 + m16] =
                (_Float16)(O[ds][r] * inv);
    }
}

// ---------------------------------------------------------------------------
extern "C" void kernel_launch(void* const* d_in, const int* in_sizes, int n_in,
                              void* d_out, int out_size, void* d_ws, size_t ws_size,
                              hipStream_t stream)
{
    (void)in_sizes; (void)n_in; (void)out_size; (void)ws_size;

    const float* x   = (const float*)d_in[0];
    const float* Bg  = (const float*)d_in[1];
    const float* Wq  = (const float*)d_in[2];
    const float* bq  = (const float*)d_in[3];
    const float* Wk  = (const float*)d_in[4];
    const float* bk  = (const float*)d_in[5];
    const float* Wv  = (const float*)d_in[6];
    const float* bv  = (const float*)d_in[7];
    const float* Wo  = (const float*)d_in[8];
    const float* bo  = (const float*)d_in[9];
    const float* lam = (const float*)d_in[10];
    float* out = (float*)d_out;
    _Float16* ws16 = (_Float16*)d_ws;

    // Workspace (f16 elems): 4*4M + 5*1M + 8M = 29M elems = 58 MiB
    constexpr size_t kQKV = (size_t)kM * kD;        // 4,194,304
    constexpr size_t kW   = (size_t)kD * kD;        // 1,048,576
    _Float16* Qf   = ws16;
    _Float16* Kf   = ws16 + 1 * kQKV;
    _Float16* Vt   = ws16 + 2 * kQKV;
    _Float16* x16  = ws16 + 3 * kQKV;
    _Float16* AOh  = x16;               // x16 dead after QKV GEMM (stream order)
    _Float16* Wt3  = ws16 + 4 * kQKV;   // [3072][1024] single-plane QKV weights
    _Float16* Woth = Wt3 + 3 * kW;
    _Float16* Wotl = Woth + kW;
    _Float16* BgC  = Wotl + kW;         // 8M f16: C-fragment-layout (lam/scale)*Bg

    dim3 blk(256);

    // 1) one-shot prep
    cvt16<<<dim3(2048), blk, 0, stream>>>(x, x16);
    bgprep<<<dim3(2048), blk, 0, stream>>>(Bg, lam, BgC);
    dim3 wg(kD / 64, kD / 64);          // (16,16)
    wcvt_t  <<<wg, blk, 0, stream>>>(Wq, Wt3);
    wcvt_t  <<<wg, blk, 0, stream>>>(Wk, Wt3 + kW);
    wcvt_t  <<<wg, blk, 0, stream>>>(Wv, Wt3 + 2 * kW);
    wsplit_t<<<wg, blk, 0, stream>>>(Wo, Woth, Wotl);

    // 2) fused QKV projection: (24, 32) = 768 blocks, 1-term
    gemm16<<<dim3(3 * kD / 128, kM / 128), blk, 34816, stream>>>(
        x16, Wt3, nullptr, bq, bk, bv, Qf, Kf, Vt, nullptr, 0);

    // 3) attention: (16, 32) = 512 blocks x 512 threads
    attn_f16<<<dim3(kN / 128, kB * kH), dim3(512), 0, stream>>>(
        Qf, Kf, Vt, BgC, AOh);

    // 4) output projection: (8, 32) = 256 blocks, 2-term
    gemm16<<<dim3(kD / 128, kM / 128), blk, 49152, stream>>>(
        AOh, Woth, Wotl, bo, nullptr, nullptr,
        nullptr, nullptr, nullptr, out, 1);
}